// Round 10
// baseline (222.864 us; speedup 1.0000x reference)
//
#include <hip/hip_runtime.h>

typedef unsigned short u16;
#define DEV __device__ __forceinline__

typedef short bf16x8 __attribute__((ext_vector_type(8)));
typedef float f32x4  __attribute__((ext_vector_type(4)));

constexpr int NP = 32768;
constexpr int C  = 128;
constexpr int NS = 16;
constexpr int RTOT = NP * NS;              // 524288 rows of [N,NS]
constexpr float EPS = 1e-5f;
constexpr float INV_R = 1.0f / (float)RTOT;

// ---- workspace layout (bytes). Measured: harness poisons 256 MiB of ws. --
constexpr size_t oXQ = 0;                              // xq bf16 8MB
constexpr size_t oXK = (size_t)NP * C * 2;             // xk bf16 8MB
constexpr size_t oXV = oXK * 2;                        // xv bf16 8MB
constexpr size_t oW1 = oXK * 3;                        // w1 logits bf16 16MB
constexpr size_t oPA = oW1 + (size_t)RTOT * 16 * 2;    // pa [512][8] f32
constexpr size_t oPB = oPA + 512*8*4;                  // pb [2048][256] f32 2MB
constexpr size_t oPC = oPB + (size_t)2048*256*4;       // pc [2048][32] f32 256KB
constexpr size_t oM1 = oPC + (size_t)2048*32*4;        // mid1[16][8]
constexpr size_t oM2 = oM1 + 16*8*4;                   // mid2[16][256]
constexpr size_t oM3 = oM2 + 16*256*4;                 // mid3[16][32]
constexpr size_t oWT = oM3 + 16*32*4;                  // Wt bf16 [3][128][128]
constexpr size_t WS_NEED = oWT + 3*128*128*2;          // ~44.4 MB << 256 MiB

DEV float bu2f(u16 v){ return __uint_as_float(((unsigned)v) << 16); }
DEV u16 f2bu(float f){
  unsigned u = __float_as_uint(f);
  return (u16)((u + 0x7fffu + ((u >> 16) & 1u)) >> 16);   // RNE
}
DEV unsigned pk2(float a, float b){ return (unsigned)f2bu(a) | ((unsigned)f2bu(b) << 16); }
DEV unsigned pk2tr(float a, float b){   // truncating bf16 pack (staging only)
  return (__float_as_uint(a) >> 16) | (__float_as_uint(b) & 0xffff0000u);
}
DEV void b2x2(unsigned v, float& lo, float& hi){
  lo = __uint_as_float(v << 16);
  hi = __uint_as_float(v & 0xffff0000u);
}
DEV int clampg(int g){ return g < 0 ? 0 : (g > NP-1 ? NP-1 : g); }

// ---------------- diagnostics ----------------
__global__ __launch_bounds__(256) void k_sig(float* __restrict__ out, float val){
  int i = blockIdx.x * 256 + threadIdx.x;
  if (i < NP*C) out[i] = val;
}

// ---------------- stage-1 partial reduce: mid[y][ch] = sum of slot chunk --
__global__ __launch_bounds__(256) void k_finA(const float* __restrict__ part,
                                              float* __restrict__ mid,
                                              int slots, int width){
  __shared__ float red[4][64];
  const int l = threadIdx.x & 63, w = threadIdx.x >> 6;
  const int ch = blockIdx.x * 64 + l;
  const int y = blockIdx.y;
  const int cs = slots >> 4;           // 16 slot-groups
  const int n4 = cs >> 2;              // per-wave slot count
  float a0 = 0.f, a1 = 0.f, a2 = 0.f, a3 = 0.f;
  if (ch < width){
    const float* base = part + (size_t)(y*cs + w*n4) * width + ch;
    int j = 0;
    for (; j + 4 <= n4; j += 4){
      a0 += base[(size_t)(j  ) * width];
      a1 += base[(size_t)(j+1) * width];
      a2 += base[(size_t)(j+2) * width];
      a3 += base[(size_t)(j+3) * width];
    }
    for (; j < n4; ++j) a0 += base[(size_t)j * width];
  }
  red[w][l] = (a0 + a1) + (a2 + a3);
  __syncthreads();
  if (threadIdx.x < 64 && ch < width)
    mid[(size_t)y * width + ch] = red[0][l] + red[1][l] + red[2][l] + red[3][l];
}

// ---------------- Wt: transpose + bf16-convert Wq/Wk/Wv -----------------
__global__ __launch_bounds__(256) void k_wt(const float* __restrict__ Wq,
                                            const float* __restrict__ Wk,
                                            const float* __restrict__ Wv,
                                            u16* __restrict__ wt){
  const int mat = blockIdx.y;
  const float* W = (mat==0) ? Wq : ((mat==1) ? Wk : Wv);
  int e = blockIdx.x * 256 + threadIdx.x;     // 64 blocks * 256 = 16384
  int k = e >> 7, c = e & 127;
  wt[mat*16384 + c*128 + k] = f2bu(W[e]);
}

// ---------------- QKV GEMM via MFMA (bf16) ------------------------------
__global__ __launch_bounds__(256) void k_qkv(const float* __restrict__ x,
                                             const u16* __restrict__ wt,
                                             const float* __restrict__ bq,
                                             const float* __restrict__ bk,
                                             const float* __restrict__ bv,
                                             u16* __restrict__ outw){
  __shared__ __align__(16) u16 xb[64*136];     // 17.4 KB
  __shared__ __align__(16) u16 wtl[128*136];   // 34.8 KB
  const int t = threadIdx.x;
  const int row0 = blockIdx.x * 64;
  {
    const float4* xs = (const float4*)(x + (size_t)row0 * C);
    #pragma unroll
    for (int i = 0; i < 8; ++i){
      int chunk = t + i*256;            // 2048 float4 chunks
      int row = chunk >> 5;             // 32 float4 per row
      int cp  = (chunk & 31) * 4;
      float4 v = xs[chunk];
      *(uint2*)&xb[row*136 + cp] = make_uint2(pk2(v.x, v.y), pk2(v.z, v.w));
    }
  }
  __syncthreads();
  const int w = t >> 6, l = t & 63;
  const int quad = l >> 4, col = l & 15;
  bf16x8 afrag[4];
  {
    const u16* abase = &xb[(size_t)(w*16 + col) * 136];
    #pragma unroll
    for (int kk = 0; kk < 4; ++kk)
      afrag[kk] = *(const bf16x8*)(abase + kk*32 + quad*8);
  }
  for (int mat = 0; mat < 3; ++mat){
    const float* bias = (mat==0) ? bq : ((mat==1) ? bk : bv);
    {
      const uint4* ws4 = (const uint4*)(wt + mat*16384);
      #pragma unroll
      for (int i = 0; i < 8; ++i){
        int chunk = t + i*256;          // 2048 chunks of 8 bf16
        int c = chunk >> 4, kp = (chunk & 15) * 8;
        *(uint4*)&wtl[c*136 + kp] = ws4[chunk];
      }
    }
    __syncthreads();
    u16* outp = outw + (size_t)mat * NP * C + (size_t)(row0 + w*16) * C;
    #pragma unroll
    for (int ct = 0; ct < 8; ++ct){
      bf16x8 bfrag[4];
      const u16* bbase = &wtl[(size_t)(ct*16 + col) * 136];
      #pragma unroll
      for (int kk = 0; kk < 4; ++kk)
        bfrag[kk] = *(const bf16x8*)(bbase + kk*32 + quad*8);
      float bv0 = bias[ct*16 + col];
      f32x4 acc; acc[0] = bv0; acc[1] = bv0; acc[2] = bv0; acc[3] = bv0;
      #pragma unroll
      for (int kk = 0; kk < 4; ++kk)
        acc = __builtin_amdgcn_mfma_f32_16x16x32_bf16(afrag[kk], bfrag[kk], acc, 0, 0, 0);
      #pragma unroll
      for (int i = 0; i < 4; ++i)
        outp[(size_t)(quad*4 + i) * C + ct*16 + col] = f2bu(acc[i]);
    }
    __syncthreads();
  }
}

// ---------------- bn1 stats -> per-block partials (no atomics) ----------
__global__ __launch_bounds__(256) void k_bn1(const float* __restrict__ p,
                                             const int* __restrict__ idx,
                                             const float* __restrict__ pW1,
                                             const float* __restrict__ pb1,
                                             float* __restrict__ partials1){
  __shared__ float wred[4][8];
  const int t = threadIdx.x;
  float w[9], b3[3];
  #pragma unroll
  for (int i = 0; i < 9; ++i) w[i] = pW1[i];
  #pragma unroll
  for (int i = 0; i < 3; ++i) b3[i] = pb1[i];
  float s[3] = {0,0,0}, q[3] = {0,0,0};
  const int base = blockIdx.x * 1024 + t;
  #pragma unroll
  for (int i = 0; i < 4; ++i){
    int r = base + i*256;
    int g = clampg(idx[r]);
    int n = r >> 4;
    float d0 = p[3*g]   - p[3*n];
    float d1 = p[3*g+1] - p[3*n+1];
    float d2 = p[3*g+2] - p[3*n+2];
    #pragma unroll
    for (int k = 0; k < 3; ++k){
      float tv = d0*w[k] + d1*w[3+k] + d2*w[6+k] + b3[k];
      s[k] += tv; q[k] = fmaf(tv, tv, q[k]);
    }
  }
  #pragma unroll
  for (int k = 0; k < 3; ++k){
    #pragma unroll
    for (int m = 1; m < 64; m <<= 1){
      s[k] += __shfl_xor(s[k], m);
      q[k] += __shfl_xor(q[k], m);
    }
  }
  if ((t & 63) == 0){
    int wv = t >> 6;
    wred[wv][0] = s[0]; wred[wv][1] = s[1]; wred[wv][2] = s[2]; wred[wv][3] = 0.f;
    wred[wv][4] = q[0]; wred[wv][5] = q[1]; wred[wv][6] = q[2]; wred[wv][7] = 0.f;
  }
  __syncthreads();
  if (t < 8)
    partials1[blockIdx.x*8 + t] = wred[0][t] + wred[1][t] + wred[2][t] + wred[3][t];
}

// ---------------- bn2 stats: full-parallel phase A, 2 barriers ----------
__global__ __launch_bounds__(256) void k_bn2(const float* __restrict__ p,
                                             const int* __restrict__ idx,
                                             const float* __restrict__ pW1,
                                             const float* __restrict__ pb1,
                                             const float* __restrict__ pg1,
                                             const float* __restrict__ pbe1,
                                             const float* __restrict__ pW2,
                                             const float* __restrict__ pb2,
                                             const u16* __restrict__ xq,
                                             const u16* __restrict__ xk,
                                             const float* __restrict__ mid1,
                                             float* __restrict__ partials2){
  __shared__ float sq0[256], sq1[256], sq2[256];
  __shared__ int   sgi[256];
  __shared__ __align__(16) float4 pW2t[128];
  __shared__ float bn1s[8];
  __shared__ __align__(16) float redS[4][128], redQ[4][128];
  const int t = threadIdx.x;
  if (t < 3){
    float sv = 0.f, sq = 0.f;
    for (int i = 0; i < 16; ++i){ sv += mid1[i*8+t]; sq += mid1[i*8+4+t]; }
    float mu = sv * INV_R, var = sq * INV_R - mu*mu;
    float rs = rsqrtf(var + EPS);
    float sc = rs * pg1[t];
    bn1s[t]   = sc;
    bn1s[4+t] = pb1[t] * sc + pbe1[t] - mu * sc;
  }
  if (t < 128)
    pW2t[t] = make_float4(pW2[t], pW2[128+t], pW2[256+t], pb2[t]);
  float w9[9];
  #pragma unroll
  for (int i = 0; i < 9; ++i) w9[i] = pW1[i];
  __syncthreads();
  {
    int r = blockIdx.x * 256 + t, n = r >> 4;
    int g = clampg(idx[r]);
    float d0 = p[3*g]   - p[3*n];
    float d1 = p[3*g+1] - p[3*n+1];
    float d2 = p[3*g+2] - p[3*n+2];
    sq0[t] = fmaxf((d0*w9[0] + d1*w9[3] + d2*w9[6]) * bn1s[0] + bn1s[4], 0.f);
    sq1[t] = fmaxf((d0*w9[1] + d1*w9[4] + d2*w9[7]) * bn1s[1] + bn1s[5], 0.f);
    sq2[t] = fmaxf((d0*w9[2] + d1*w9[5] + d2*w9[8]) * bn1s[2] + bn1s[6], 0.f);
    sgi[t] = g;
  }
  __syncthreads();
  const int w = t >> 6, l = t & 63;
  const float4 pwA = pW2t[2*l], pwB = pW2t[2*l+1];
  float sA = 0.f, qA = 0.f, sB = 0.f, qB = 0.f;
  #pragma unroll
  for (int pp = 0; pp < 4; ++pp){
    const int nl = w*4 + pp;                  // wave-local point (16/block)
    const int n  = blockIdx.x*16 + nl;
    unsigned qx = *(const unsigned*)(xq + (size_t)n*C + 2*l);
    float xqA, xqB; b2x2(qx, xqA, xqB);
    #pragma unroll
    for (int j = 0; j < 16; ++j){
      int rr = nl*16 + j;
      int g = sgi[rr];
      unsigned kx = *(const unsigned*)(xk + (size_t)g*C + 2*l);
      float xkA, xkB; b2x2(kx, xkA, xkB);
      float prA = sq0[rr]*pwA.x + sq1[rr]*pwA.y + sq2[rr]*pwA.z + pwA.w;
      float prB = sq0[rr]*pwB.x + sq1[rr]*pwB.y + sq2[rr]*pwB.z + pwB.w;
      float w0A = xkA - xqA + prA;
      float w0B = xkB - xqB + prB;
      sA += w0A; qA = fmaf(w0A, w0A, qA);
      sB += w0B; qB = fmaf(w0B, w0B, qB);
    }
  }
  *(float2*)&redS[w][2*l] = make_float2(sA, sB);
  *(float2*)&redQ[w][2*l] = make_float2(qA, qB);
  __syncthreads();
  if (t < 128){
    partials2[(size_t)blockIdx.x*256 + t]       = redS[0][t]+redS[1][t]+redS[2][t]+redS[3][t];
    partials2[(size_t)blockIdx.x*256 + 128 + t] = redQ[0][t]+redQ[1][t]+redQ[2][t]+redQ[3][t];
  }
}

// ---------------- w1 = relu(bn2(w0)) @ wW1 + wb1 ; MFMA + fused bn3 -----
__global__ __launch_bounds__(256) void k_w1(const float* __restrict__ p,
                                            const int* __restrict__ idx,
                                            const float* __restrict__ pW1,
                                            const float* __restrict__ pb1,
                                            const float* __restrict__ pg1,
                                            const float* __restrict__ pbe1,
                                            const float* __restrict__ pW2,
                                            const float* __restrict__ pb2,
                                            const float* __restrict__ wg1,
                                            const float* __restrict__ wbe1,
                                            const float* __restrict__ wW1,
                                            const float* __restrict__ wb1,
                                            const u16* __restrict__ xq,
                                            const u16* __restrict__ xk,
                                            u16* __restrict__ w1out,
                                            const float* __restrict__ mid1,
                                            const float* __restrict__ mid2,
                                            float* __restrict__ pc){
  __shared__ __align__(16) float4 pW2t[128];
  __shared__ float2 ss2[128];
  __shared__ float bn1s[8];
  __shared__ float wb1f[16];
  __shared__ float pW1f[9];
  __shared__ float sq0[256], sq1[256], sq2[256];
  __shared__ int   sgi[256];
  __shared__ __align__(16) u16 hsb[64*136];   // bf16 h, 17.4 KB, pad 136
  __shared__ float wredS[4][16], wredQ[4][16];
  const int t = threadIdx.x;
  if (t < 3){
    float sv = 0.f, sq = 0.f;
    for (int i = 0; i < 16; ++i){ sv += mid1[i*8+t]; sq += mid1[i*8+4+t]; }
    float mu = sv * INV_R, var = sq * INV_R - mu*mu;
    float rs = rsqrtf(var + EPS);
    float sc = rs * pg1[t];
    bn1s[t]   = sc;
    bn1s[4+t] = pb1[t] * sc + pbe1[t] - mu * sc;
  }
  if (t < 9)  pW1f[t] = pW1[t];
  if (t < 16) wb1f[t] = wb1[t];
  if (t < 128){
    pW2t[t] = make_float4(pW2[t], pW2[128+t], pW2[256+t], pb2[t]);
    float sv = 0.f, sq = 0.f;
    for (int i = 0; i < 16; ++i){ sv += mid2[i*256+t]; sq += mid2[i*256+128+t]; }
    float mu = sv * INV_R, var = sq * INV_R - mu*mu;
    float rs = rsqrtf(var + EPS);
    float sc = rs * wg1[t];
    ss2[t] = make_float2(sc, wbe1[t] - mu * sc);
  }
  const int w = t >> 6, l = t & 63;
  const int quad = l >> 4, col = l & 15;
  bf16x8 bfrag[4];
  #pragma unroll
  for (int kk = 0; kk < 4; ++kk){
    #pragma unroll
    for (int j = 0; j < 8; ++j)
      bfrag[kk][j] = (short)f2bu(wW1[(size_t)(kk*32 + quad*8 + j)*16 + col]);
  }
  __syncthreads();
  {
    int r = blockIdx.x * 256 + t, n = r >> 4;
    int g = clampg(idx[r]);
    float d0 = p[3*g]   - p[3*n];
    float d1 = p[3*g+1] - p[3*n+1];
    float d2 = p[3*g+2] - p[3*n+2];
    sq0[t] = fmaxf((d0*pW1f[0] + d1*pW1f[3] + d2*pW1f[6]) * bn1s[0] + bn1s[4], 0.f);
    sq1[t] = fmaxf((d0*pW1f[1] + d1*pW1f[4] + d2*pW1f[7]) * bn1s[1] + bn1s[5], 0.f);
    sq2[t] = fmaxf((d0*pW1f[2] + d1*pW1f[5] + d2*pW1f[8]) * bn1s[2] + bn1s[6], 0.f);
    sgi[t] = g;
  }
  __syncthreads();

  const float4 pwA = pW2t[2*l], pwB = pW2t[2*l+1];
  const float2 scA = ss2[2*l],  scB = ss2[2*l+1];
  const float biasC = wb1f[col];
  float sSt = 0.f, qSt = 0.f;            // fused bn3 per-lane partials

  for (int tile = 0; tile < 4; ++tile){
    {
      const int nl = tile*4 + w;
      const int n  = blockIdx.x*16 + nl;
      unsigned qx = *(const unsigned*)(xq + (size_t)n*C + 2*l);
      float xqA, xqB; b2x2(qx, xqA, xqB);
      #pragma unroll
      for (int j = 0; j < 16; ++j){
        int rrb = nl*16 + j;             // block-space row
        int g = sgi[rrb];
        unsigned kx = *(const unsigned*)(xk + (size_t)g*C + 2*l);
        float xkA, xkB; b2x2(kx, xkA, xkB);
        float prA = sq0[rrb]*pwA.x + sq1[rrb]*pwA.y + sq2[rrb]*pwA.z + pwA.w;
        float prB = sq0[rrb]*pwB.x + sq1[rrb]*pwB.y + sq2[rrb]*pwB.z + pwB.w;
        float hA = fmaxf(fmaf(xkA - xqA + prA, scA.x, scA.y), 0.f);
        float hB = fmaxf(fmaf(xkB - xqB + prB, scB.x, scB.y), 0.f);
        *(unsigned*)&hsb[(w*16 + j)*136 + 2*l] = pk2tr(hA, hB);
      }
    }
    __syncthreads();
    f32x4 acc;
    acc[0] = biasC; acc[1] = biasC; acc[2] = biasC; acc[3] = biasC;
    const u16* hbase = &hsb[(size_t)(w*16 + col) * 136];
    #pragma unroll
    for (int kk = 0; kk < 4; ++kk){
      bf16x8 af = *(const bf16x8*)(hbase + kk*32 + quad*8);
      acc = __builtin_amdgcn_mfma_f32_16x16x32_bf16(af, bfrag[kk], acc, 0, 0, 0);
    }
    const int rowbase = blockIdx.x*256 + tile*64 + w*16 + quad*4;
    #pragma unroll
    for (int i = 0; i < 4; ++i){
      w1out[(size_t)(rowbase + i) * 16 + col] = f2bu(acc[i]);
      sSt += acc[i];
      qSt = fmaf(acc[i], acc[i], qSt);
    }
    __syncthreads();
  }
  sSt += __shfl_xor(sSt, 16); sSt += __shfl_xor(sSt, 32);
  qSt += __shfl_xor(qSt, 16); qSt += __shfl_xor(qSt, 32);
  if (l < 16){ wredS[w][l] = sSt; wredQ[w][l] = qSt; }
  __syncthreads();
  if (t < 16)
    pc[(size_t)blockIdx.x*32 + t] = wredS[0][t]+wredS[1][t]+wredS[2][t]+wredS[3][t];
  else if (t < 32){
    int c = t - 16;
    pc[(size_t)blockIdx.x*32 + 16 + c] = wredQ[0][c]+wredQ[1][c]+wredQ[2][c]+wredQ[3][c];
  }
}

// ---------------- final: bn3 -> relu -> wW2 -> softmax(j) -> aggregate --
// s_w2 padded to 17 floats/row: 17 odd => 17*row mod 32 bijective over any
// 32 rows => write phase and softmax phase are conflict-free (were 32-way).
__global__ __launch_bounds__(256) void k_out(const float* __restrict__ p,
                                             const int* __restrict__ idx,
                                             const float* __restrict__ pW1,
                                             const float* __restrict__ pb1,
                                             const float* __restrict__ pg1,
                                             const float* __restrict__ pbe1,
                                             const float* __restrict__ pW2,
                                             const float* __restrict__ pb2,
                                             const float* __restrict__ wg2,
                                             const float* __restrict__ wbe2,
                                             const float* __restrict__ wW2,
                                             const float* __restrict__ wb2,
                                             const u16* __restrict__ xv,
                                             const u16* __restrict__ w1ws,
                                             const float* __restrict__ mid1,
                                             const float* __restrict__ mid3,
                                             float* __restrict__ out){
  __shared__ __align__(16) float4 pW2t[128];
  __shared__ float pW1f[9];
  __shared__ float bn1s[8];
  __shared__ float sc3[16], sh3[16], wb2f[16];
  __shared__ float wW2f[256];
  __shared__ float s_w2[256*17];
  __shared__ float s_q0[256], s_q1[256], s_q2[256];
  __shared__ int   s_g[256];
  const int t = threadIdx.x;
  if (t < 3){
    float sv = 0.f, sq = 0.f;
    for (int i = 0; i < 16; ++i){ sv += mid1[i*8+t]; sq += mid1[i*8+4+t]; }
    float mu = sv * INV_R, var = sq * INV_R - mu*mu;
    float rs = rsqrtf(var + EPS);
    float sc = rs * pg1[t];
    bn1s[t]   = sc;
    bn1s[4+t] = pb1[t] * sc + pbe1[t] - mu * sc;
  }
  if (t < 9) pW1f[t] = pW1[t];
  if (t < 16){
    float sv = 0.f, sq = 0.f;
    for (int i = 0; i < 16; ++i){ sv += mid3[i*32+t]; sq += mid3[i*32+16+t]; }
    float mu = sv * INV_R, var = sq * INV_R - mu*mu;
    float rs = rsqrtf(var + EPS);
    float sc = rs * wg2[t];
    sc3[t] = sc;
    sh3[t] = wbe2[t] - mu * sc;
    wb2f[t] = wb2[t];
  }
  if (t < 128)
    pW2t[t] = make_float4(pW2[t], pW2[128+t], pW2[256+t], pb2[t]);
  wW2f[t] = wW2[t];
  __syncthreads();

  const int pt = t >> 4;
  const int jj = t & 15;
  const int n0 = blockIdx.x * 16;
  {
    const int n = n0 + pt;
    const int r = n * NS + jj;
    const int g = clampg(idx[r]);
    float d0 = p[3*g]   - p[3*n];
    float d1 = p[3*g+1] - p[3*n+1];
    float d2 = p[3*g+2] - p[3*n+2];
    s_q0[t] = fmaxf((d0*pW1f[0] + d1*pW1f[3] + d2*pW1f[6]) * bn1s[0] + bn1s[4], 0.f);
    s_q1[t] = fmaxf((d0*pW1f[1] + d1*pW1f[4] + d2*pW1f[7]) * bn1s[1] + bn1s[5], 0.f);
    s_q2[t] = fmaxf((d0*pW1f[2] + d1*pW1f[5] + d2*pW1f[8]) * bn1s[2] + bn1s[6], 0.f);
    s_g[t]  = g;
    const uint4* wp = (const uint4*)(w1ws + (size_t)r * 16);
    uint4 Wa = wp[0], Wb = wp[1];
    float h2[16];
    #pragma unroll
    for (int o2 = 0; o2 < 4; ++o2){
      float lo, hi;
      b2x2((&Wa.x)[o2], lo, hi);
      h2[o2*2]     = fmaxf(lo * sc3[o2*2]     + sh3[o2*2],     0.f);
      h2[o2*2+1]   = fmaxf(hi * sc3[o2*2+1]   + sh3[o2*2+1],   0.f);
      b2x2((&Wb.x)[o2], lo, hi);
      h2[8+o2*2]   = fmaxf(lo * sc3[8+o2*2]   + sh3[8+o2*2],   0.f);
      h2[8+o2*2+1] = fmaxf(hi * sc3[8+o2*2+1] + sh3[8+o2*2+1], 0.f);
    }
    float w2[16];
    #pragma unroll
    for (int o = 0; o < 16; ++o) w2[o] = wb2f[o];
    #pragma unroll
    for (int o2 = 0; o2 < 16; ++o2){
      float h = h2[o2];
      const float* wr = &wW2f[o2*16];
      #pragma unroll
      for (int o = 0; o < 16; ++o) w2[o] = fmaf(h, wr[o], w2[o]);
    }
    float* dst = &s_w2[(pt*16 + jj)*17];
    #pragma unroll
    for (int o = 0; o < 16; ++o) dst[o] = w2[o];
  }
  __syncthreads();
  const int cs = t & 15;
  {
    float mx = -1e30f;
    #pragma unroll
    for (int j2 = 0; j2 < 16; ++j2) mx = fmaxf(mx, s_w2[(pt*16+j2)*17 + cs]);
    float e[16]; float sum = 0.f;
    #pragma unroll
    for (int j2 = 0; j2 < 16; ++j2){
      e[j2] = __expf(s_w2[(pt*16+j2)*17 + cs] - mx);
      sum += e[j2];
    }
    float inv = 1.0f / sum;
    #pragma unroll
    for (int j2 = 0; j2 < 16; ++j2) s_w2[(pt*16+j2)*17 + cs] = e[j2] * inv;
  }
  __syncthreads();
  const int w = t >> 6, l = t & 63;
  const float4 pwA = pW2t[2*l], pwB = pW2t[2*l+1];
  const int csA = (2*l) & 15;
  #pragma unroll
  for (int pp = 0; pp < 4; ++pp){
    const int pt2 = pp * 4 + w;
    const int n = n0 + pt2;
    float accA = 0.f, accB = 0.f;
    #pragma unroll
    for (int j = 0; j < 16; ++j){
      const int base = pt2*16 + j;
      float pjA = s_w2[base*17 + csA];
      float pjB = s_w2[base*17 + csA + 1];
      int g = s_g[base];
      float qa = s_q0[base], qb = s_q1[base], qc = s_q2[base];
      unsigned v = *(const unsigned*)(xv + (size_t)g*C + 2*l);
      float xvA, xvB; b2x2(v, xvA, xvB);
      float prA = qa*pwA.x + qb*pwA.y + qc*pwA.z + pwA.w;
      float prB = qa*pwB.x + qb*pwB.y + qc*pwB.z + pwB.w;
      accA = fmaf(xvA + prA, pjA, accA);
      accB = fmaf(xvB + prB, pjB, accB);
    }
    *(float2*)(out + (size_t)n*C + 2*l) = make_float2(accA, accB);
  }
}

extern "C" void kernel_launch(void* const* d_in, const int* in_sizes, int n_in,
                              void* d_out, int out_size, void* d_ws, size_t ws_size,
                              hipStream_t stream) {
  bool ok = (n_in == 23) && (out_size == NP*C) &&
            in_sizes[0] == NP*3 && in_sizes[1] == NP*C &&
            in_sizes[2] == C*C  && in_sizes[8] == 9 &&
            in_sizes[12] == 3*C && in_sizes[16] == C*(C/8) &&
            in_sizes[20] == (C/8)*(C/8) && in_sizes[22] == RTOT;
  if (!ok){
    k_sig<<<(NP*C+255)/256, 256, 0, stream>>>((float*)d_out, 10000.0f);
    return;
  }
  if (ws_size < WS_NEED){
    k_sig<<<(NP*C+255)/256, 256, 0, stream>>>((float*)d_out, 20000.0f);
    return;
  }
  const float* p    = (const float*)d_in[0];
  const float* x    = (const float*)d_in[1];
  const float* Wq   = (const float*)d_in[2];
  const float* bq   = (const float*)d_in[3];
  const float* Wk   = (const float*)d_in[4];
  const float* bk   = (const float*)d_in[5];
  const float* Wv   = (const float*)d_in[6];
  const float* bv   = (const float*)d_in[7];
  const float* pW1  = (const float*)d_in[8];
  const float* pb1  = (const float*)d_in[9];
  const float* pg1  = (const float*)d_in[10];
  const float* pbe1 = (const float*)d_in[11];
  const float* pW2  = (const float*)d_in[12];
  const float* pb2  = (const float*)d_in[13];
  const float* wg1  = (const float*)d_in[14];
  const float* wbe1 = (const float*)d_in[15];
  const float* wW1  = (const float*)d_in[16];
  const float* wb1  = (const float*)d_in[17];
  const float* wg2  = (const float*)d_in[18];
  const float* wbe2 = (const float*)d_in[19];
  const float* wW2  = (const float*)d_in[20];
  const float* wb2  = (const float*)d_in[21];
  const int* idx    = (const int*)d_in[22];

  char* ws = (char*)d_ws;
  u16* xq    = (u16*)(ws + oXQ);
  u16* xk    = (u16*)(ws + oXK);
  u16* xv    = (u16*)(ws + oXV);
  u16* w1ws  = (u16*)(ws + oW1);
  float* pa  = (float*)(ws + oPA);
  float* pb  = (float*)(ws + oPB);
  float* pc  = (float*)(ws + oPC);
  float* m1  = (float*)(ws + oM1);
  float* m2  = (float*)(ws + oM2);
  float* m3  = (float*)(ws + oM3);
  u16* wtp   = (u16*)(ws + oWT);

  k_wt <<<dim3(64, 3), 256, 0, stream>>>(Wq, Wk, Wv, wtp);
  k_qkv<<<512, 256, 0, stream>>>(x, wtp, bq, bk, bv, xq);
  k_bn1<<<512, 256, 0, stream>>>(p, idx, pW1, pb1, pa);
  k_finA<<<dim3(1, 16), 256, 0, stream>>>(pa, m1, 512, 8);
  k_bn2<<<2048, 256, 0, stream>>>(p, idx, pW1, pb1, pg1, pbe1, pW2, pb2,
                                  xq, xk, m1, pb);
  k_finA<<<dim3(4, 16), 256, 0, stream>>>(pb, m2, 2048, 256);
  k_w1 <<<2048, 256, 0, stream>>>(p, idx, pW1, pb1, pg1, pbe1, pW2, pb2,
                                  wg1, wbe1, wW1, wb1, xq, xk, w1ws, m1, m2, pc);
  k_finA<<<dim3(1, 16), 256, 0, stream>>>(pc, m3, 2048, 32);
  k_out<<<2048, 256, 0, stream>>>(p, idx, pW1, pb1, pg1, pbe1, pW2, pb2,
                                  wg2, wbe2, wW2, wb2, xv, w1ws, m1, m3,
                                  (float*)d_out);
}